// Round 1
// baseline (3744.556 us; speedup 1.0000x reference)
//
#include <hip/hip_runtime.h>

// WaveNet-ish residual stack: 40 blocks, dilated causal conv (k=2) -> relu ->
// {1x1 conv + residual, 1x1 skip}. fp32 baseline, fused per-block kernel.
//
// Shapes: x [4][64][8192], dc_w [40][64][64][2], dc_b [40][64],
// conv_w [40][64][64], conv_b [40][64], skip_w [40][256][64], skip_b [40][256]
// out: [40][4][256][4096] fp32.

#define CC    64      // residual channels
#define SCC   256     // skip channels
#define BB    4       // batch
#define LL0   8192    // initial length (also the fixed row stride of ping-pong bufs)
#define NBLK  40
#define SKIPN 4096
#define TT    64      // time tile per workgroup
#define PADW  68      // padded LDS row stride (floats), 16B-aligned rows

__global__ __launch_bounds__(256) void prep_transpose(
    const float* __restrict__ dc_w, const float* __restrict__ conv_w,
    const float* __restrict__ skip_w,
    float* __restrict__ wt0, float* __restrict__ wt1,
    float* __restrict__ cwt, float* __restrict__ swt)
{
    const int n_dc = NBLK * CC * CC;    // 163840
    const int n_sw = NBLK * CC * SCC;   // 655360
    for (int idx = blockIdx.x * blockDim.x + threadIdx.x; idx < n_sw;
         idx += gridDim.x * blockDim.x) {
        if (idx < n_dc) {
            // target layout [i][k][o]
            const int o = idx & 63, k = (idx >> 6) & 63, i = idx >> 12;
            const int s = (i * CC + o) * CC + k;   // src [i][o][k]
            wt0[idx] = dc_w[s * 2 + 0];
            wt1[idx] = dc_w[s * 2 + 1];
            cwt[idx] = conv_w[s];
        }
        // target layout [i][k][so]
        const int so = idx & 255, k2 = (idx >> 8) & 63, i2 = idx >> 14;
        swt[idx] = skip_w[(i2 * SCC + so) * CC + k2];
    }
}

// One residual block. cur/nxt are [BB][CC][LL0] with logical lengths Lin/Lout.
__global__ __launch_bounds__(256) void block_kernel(
    const float* __restrict__ cur, float* __restrict__ nxt,
    const float* __restrict__ wt0, const float* __restrict__ wt1,
    const float* __restrict__ cwt, const float* __restrict__ swt,
    const float* __restrict__ db, const float* __restrict__ cb,
    const float* __restrict__ sb, float* __restrict__ skip_out,
    int d, int Lin, int Lout, int ntiles)
{
    __shared__ float xs0[CC][PADW];   // x[t]        (later reused as r+residual)
    __shared__ float xs1[CC][PADW];   // x[t+d]
    __shared__ float gs[CC][PADW];    // relu(h)

    const int tid  = threadIdx.x;
    const int lane = tid & 63;
    const int wave = tid >> 6;
    const int b    = blockIdx.x / ntiles;
    const int t0   = (blockIdx.x % ntiles) * TT;

    const float* src = cur + (size_t)b * CC * LL0;

    // ---- stage x0/x1 tiles into LDS (coalesced float4 when possible) ----
    {
        const int row = tid >> 2;            // 0..63 channel
        const int c0  = (tid & 3) * 16;      // 16 consecutive columns / thread
        const float* srow = src + (size_t)row * LL0;
        const bool vec_ok = (t0 + TT + d <= Lin) && ((d & 3) == 0);
        if (vec_ok) {
            #pragma unroll
            for (int q = 0; q < 4; ++q) {
                const int c = c0 + q * 4;
                *(float4*)&xs0[row][c] = *(const float4*)(srow + t0 + c);
                *(float4*)&xs1[row][c] = *(const float4*)(srow + t0 + c + d);
            }
        } else {
            #pragma unroll
            for (int j = 0; j < 16; ++j) {
                const int c = c0 + j;
                int ta = t0 + c;     if (ta > Lin - 1) ta = Lin - 1;
                int tb_ = t0 + c + d; if (tb_ > Lin - 1) tb_ = Lin - 1;
                xs0[row][c] = srow[ta];   // clamped values only feed dead columns
                xs1[row][c] = srow[tb_];
            }
        }
    }
    __syncthreads();

    const int tb = wave * 16;   // this wave's 16 time columns

    // ---- dilated conv + bias + relu -> gs (lane = out channel) ----
    {
        float acc[16];
        const float bias = db[lane];
        #pragma unroll
        for (int j = 0; j < 16; ++j) acc[j] = bias;
        #pragma unroll 4
        for (int k = 0; k < CC; ++k) {
            const float w0 = wt0[k * CC + lane];
            const float w1 = wt1[k * CC + lane];
            const float4* p0 = (const float4*)&xs0[k][tb];
            const float4* p1 = (const float4*)&xs1[k][tb];
            #pragma unroll
            for (int q = 0; q < 4; ++q) {
                const float4 a = p0[q], v = p1[q];
                acc[q * 4 + 0] += w0 * a.x + w1 * v.x;
                acc[q * 4 + 1] += w0 * a.y + w1 * v.y;
                acc[q * 4 + 2] += w0 * a.z + w1 * v.z;
                acc[q * 4 + 3] += w0 * a.w + w1 * v.w;
            }
        }
        #pragma unroll
        for (int j = 0; j < 16; ++j)
            gs[lane][tb + j] = acc[j] > 0.f ? acc[j] : 0.f;
    }
    // gs columns tb..tb+15 are produced and consumed by the SAME wave below
    // (dc wrote all rows for this wave's columns) -> no barrier needed yet.

    // ---- 1x1 conv + residual -> rs (reusing xs0; columns are wave-private) ----
    {
        float acc[16];
        const float bias = cb[lane];
        #pragma unroll
        for (int j = 0; j < 16; ++j) acc[j] = bias;
        #pragma unroll 4
        for (int k = 0; k < CC; ++k) {
            const float wc = cwt[k * CC + lane];
            const float4* pg = (const float4*)&gs[k][tb];
            #pragma unroll
            for (int q = 0; q < 4; ++q) {
                const float4 g = pg[q];
                acc[q * 4 + 0] += wc * g.x;
                acc[q * 4 + 1] += wc * g.y;
                acc[q * 4 + 2] += wc * g.z;
                acc[q * 4 + 3] += wc * g.w;
            }
        }
        #pragma unroll
        for (int j = 0; j < 16; ++j)
            xs0[lane][tb + j] = acc[j] + xs1[lane][tb + j];   // residual = x[t+d]
    }
    __syncthreads();   // rs + gs now visible to all waves

    // ---- coalesced writeout of nxt ----
    {
        const int row = tid >> 2;
        const int c0  = (tid & 3) * 16;
        float* drow = nxt + (size_t)b * CC * LL0 + (size_t)row * LL0;
        if (t0 + TT <= Lout) {
            #pragma unroll
            for (int q = 0; q < 4; ++q) {
                const int c = c0 + q * 4;
                *(float4*)(drow + t0 + c) = *(const float4*)&xs0[row][c];
            }
        } else {
            #pragma unroll
            for (int j = 0; j < 16; ++j) {
                const int c = c0 + j;
                if (t0 + c < Lout) drow[t0 + c] = xs0[row][c];
            }
        }
    }

    // ---- skip matmul, only for columns in the last-SKIPN window ----
    const int skip_start = Lout - SKIPN;
    if (t0 + TT - 1 >= skip_start) {
        const int t = t0 + lane;                     // lane = time column
        const bool in_range = (t >= skip_start) && (t < Lout);
        const int toff = t - skip_start;
        float* sk_b = skip_out + (size_t)b * SCC * SKIPN;
        const int so0 = wave * 64;                   // 64 skip channels / wave
        for (int sc = so0; sc < so0 + 64; sc += 8) {
            float a[8];
            #pragma unroll
            for (int j = 0; j < 8; ++j) a[j] = sb[sc + j];
            #pragma unroll 2
            for (int k = 0; k < CC; ++k) {
                const float gk = gs[k][lane];                      // lane-consecutive
                const float4 w0 = *(const float4*)&swt[k * SCC + sc];      // uniform -> s_load
                const float4 w1 = *(const float4*)&swt[k * SCC + sc + 4];
                a[0] += w0.x * gk; a[1] += w0.y * gk;
                a[2] += w0.z * gk; a[3] += w0.w * gk;
                a[4] += w1.x * gk; a[5] += w1.y * gk;
                a[6] += w1.z * gk; a[7] += w1.w * gk;
            }
            if (in_range) {
                #pragma unroll
                for (int j = 0; j < 8; ++j)
                    sk_b[(size_t)(sc + j) * SKIPN + toff] = a[j];  // coalesced over t
            }
        }
    }
}

extern "C" void kernel_launch(void* const* d_in, const int* in_sizes, int n_in,
                              void* d_out, int out_size, void* d_ws, size_t ws_size,
                              hipStream_t stream)
{
    const float* x      = (const float*)d_in[0];
    const float* dc_w   = (const float*)d_in[1];
    const float* dc_b   = (const float*)d_in[2];
    const float* conv_w = (const float*)d_in[3];
    const float* conv_b = (const float*)d_in[4];
    const float* skip_w = (const float*)d_in[5];
    const float* skip_b = (const float*)d_in[6];
    float* out = (float*)d_out;

    // workspace layout (floats): buf0, buf1 (ping-pong activations), transposed weights
    float* ws   = (float*)d_ws;
    float* buf0 = ws;
    float* buf1 = buf0 + (size_t)BB * CC * LL0;          // 2097152 floats each
    float* wt0  = buf1 + (size_t)BB * CC * LL0;
    float* wt1  = wt0 + NBLK * CC * CC;                  // 163840 each
    float* cwt  = wt1 + NBLK * CC * CC;
    float* swt  = cwt + NBLK * CC * CC;                  // 655360
    // total ~5.34M floats ~= 21.4 MB

    hipMemcpyAsync(buf0, x, (size_t)BB * CC * LL0 * sizeof(float),
                   hipMemcpyDeviceToDevice, stream);
    prep_transpose<<<2560, 256, 0, stream>>>(dc_w, conv_w, skip_w, wt0, wt1, cwt, swt);

    int dil[NBLK];
    for (int s = 0; s < 4; ++s)
        for (int l = 0; l < 10; ++l) dil[s * 10 + l] = 1 << l;

    int Lc = LL0;
    for (int i = 0; i < NBLK; ++i) {
        const int d    = dil[i];
        const int Lout = Lc - d;
        const int ntiles = (Lout + TT - 1) / TT;
        const float* curp = (i & 1) ? buf1 : buf0;
        float*       nxtp = (i & 1) ? buf0 : buf1;
        block_kernel<<<dim3(BB * ntiles), 256, 0, stream>>>(
            curp, nxtp,
            wt0 + i * CC * CC, wt1 + i * CC * CC, cwt + i * CC * CC,
            swt + i * CC * SCC,
            dc_b + i * CC, conv_b + i * CC, skip_b + i * SCC,
            out + (size_t)i * BB * SCC * SKIPN,
            d, Lc, Lout, ntiles);
        Lc = Lout;
    }
}

// Round 2
// 1071.109 us; speedup vs baseline: 3.4960x; 3.4960x over previous
//
#include <hip/hip_runtime.h>

// WaveNet residual stack, MFMA bf16 version.
// Residual stream kept fp32 in ping-pong buffers; matmul operands cast to bf16.
// Per block: H^T[t][o] = [X0|X1]^T[t][kk] . Wcat[o][kk]  (K=128 MFMA GEMM)
//            G = relu(H + db);  R^T = G^T . CW^T;  OUT = R + X1 (fp32)
// g window (last 4096 t) stored bf16 [t][c]; one big deferred skip GEMM kernel
// produces out[40][4][256][4096] fp32.

#define CC    64
#define SCC   256
#define BB    4
#define LL0   8192
#define NBLK  40
#define SKIPN 4096
#define TT    64

typedef __attribute__((ext_vector_type(8))) short bf16x8;
typedef __attribute__((ext_vector_type(4))) float f32x4;

__device__ __forceinline__ unsigned short f2bf(float f) {
    union { float f; unsigned u; } v; v.f = f;
    return (unsigned short)((v.u + 0x7FFF + ((v.u >> 16) & 1)) >> 16);
}

// ---- weight prep: bf16 casts + dc-weight concat [o][kk], kk<64->w0, >=64->w1 ----
__global__ __launch_bounds__(256) void prep_weights(
    const float* __restrict__ dc_w, const float* __restrict__ conv_w,
    const float* __restrict__ skip_w,
    unsigned short* __restrict__ wcat,  // [NBLK][64][128]
    unsigned short* __restrict__ cwb,   // [NBLK][64][64]   (= conv_w layout)
    unsigned short* __restrict__ swb)   // [NBLK][256][64]  (= skip_w layout)
{
    const int n_sw = NBLK * SCC * CC;   // 655360
    const int n_cw = NBLK * CC * CC;    // 163840
    const int n_wc = NBLK * CC * 128;   // 327680
    for (int idx = blockIdx.x * blockDim.x + threadIdx.x; idx < n_sw;
         idx += gridDim.x * blockDim.x) {
        swb[idx] = f2bf(skip_w[idx]);
        if (idx < n_cw) cwb[idx] = f2bf(conv_w[idx]);
        if (idx < n_wc) {
            const int i = idx >> 13, o = (idx >> 7) & 63, kk = idx & 127;
            wcat[idx] = f2bf(dc_w[(((i * CC + o) * CC) + (kk & 63)) * 2 + (kk >> 6)]);
        }
    }
}

// ---- one residual block ----
__global__ __launch_bounds__(256) void block_kernel(
    const float* __restrict__ cur, float* __restrict__ nxt,
    const unsigned short* __restrict__ wcat, const unsigned short* __restrict__ cwb,
    const float* __restrict__ db, const float* __restrict__ cb,
    unsigned short* __restrict__ g_out,   // [BB][SKIPN][CC] bf16
    int d, int Lin, int Lout, int ntiles)
{
    // xt: [t][kk] bf16, 64 rows x 256B, XOR-swizzled 16B chunks (chunk ^= row&7)
    // gs: [t][o]  bf16, 64 rows x 128B, same swizzle
    __shared__ __align__(16) unsigned short xt[TT * 128];
    __shared__ __align__(16) unsigned short gs[TT * CC];

    const int tid  = threadIdx.x;
    const int lane = tid & 63;
    const int wv   = tid >> 6;
    const int b    = blockIdx.x / ntiles;
    const int t0   = (blockIdx.x % ntiles) * TT;
    const float* src = cur + (size_t)b * CC * LL0;

    // ---- stage X0 (kk=c) / X1 (kk=64+c) fp32 -> bf16, transposed to [t][kk] ----
    {
        const int c  = (tid & 31) * 2;   // channel pair (c, c+1)
        const int tg = tid >> 5;         // 0..7 -> rows tg*8 .. tg*8+7
        #pragma unroll
        for (int op = 0; op < 2; ++op) {
            const int doff = op ? d : 0;
            const int tb = t0 + tg * 8 + doff;
            float v0[8], v1[8];
            if (tb + 7 <= Lin - 1 && (tb & 3) == 0) {
                *(float4*)&v0[0] = *(const float4*)(src + (size_t)c * LL0 + tb);
                *(float4*)&v0[4] = *(const float4*)(src + (size_t)c * LL0 + tb + 4);
                *(float4*)&v1[0] = *(const float4*)(src + (size_t)(c + 1) * LL0 + tb);
                *(float4*)&v1[4] = *(const float4*)(src + (size_t)(c + 1) * LL0 + tb + 4);
            } else {
                #pragma unroll
                for (int j = 0; j < 8; ++j) {
                    int t = tb + j; if (t > Lin - 1) t = Lin - 1;
                    v0[j] = src[(size_t)c * LL0 + t];
                    v1[j] = src[(size_t)(c + 1) * LL0 + t];
                }
            }
            const int kk = op * 64 + c;
            const int chunk = kk >> 3, sub = kk & 7;
            #pragma unroll
            for (int j = 0; j < 8; ++j) {
                const int row = tg * 8 + j;
                const unsigned pack = (unsigned)f2bf(v0[j]) | ((unsigned)f2bf(v1[j]) << 16);
                *(unsigned*)((char*)xt + row * 256 + ((chunk ^ (row & 7)) * 16) + sub * 2) = pack;
            }
        }
    }
    __syncthreads();

    // ---- GEMM1: wave wv owns t rows [wv*16, wv*16+16), all 64 o ----
    bf16x8 a1[4];
    {
        const int row = wv * 16 + (lane & 15);
        #pragma unroll
        for (int ks = 0; ks < 4; ++ks) {
            const int chunk = ks * 4 + (lane >> 4);
            a1[ks] = *(const bf16x8*)((const char*)xt + row * 256 + ((chunk ^ (row & 7)) * 16));
        }
    }
    f32x4 acc[4];
    #pragma unroll
    for (int n = 0; n < 4; ++n) {
        const int o = n * 16 + (lane & 15);
        const float bias = db[o];
        acc[n] = (f32x4){bias, bias, bias, bias};
        const unsigned short* wrow = wcat + o * 128 + (lane >> 4) * 8;
        #pragma unroll
        for (int ks = 0; ks < 4; ++ks)
            acc[n] = __builtin_amdgcn_mfma_f32_16x16x32_bf16(
                a1[ks], *(const bf16x8*)(wrow + ks * 32), acc[n], 0, 0, 0);
    }
    // relu -> gs
    {
        const int trow0 = wv * 16 + ((lane >> 4) << 2);
        #pragma unroll
        for (int n = 0; n < 4; ++n) {
            const int o = n * 16 + (lane & 15);
            const int chunkb = o >> 3, sub = o & 7;
            #pragma unroll
            for (int r = 0; r < 4; ++r) {
                float g = acc[n][r]; g = g > 0.f ? g : 0.f;
                const int row = trow0 + r;
                *(unsigned short*)((char*)gs + row * 128 + ((chunkb ^ (row & 7)) * 16) + sub * 2) = f2bf(g);
            }
        }
    }
    __syncthreads();

    // ---- GEMM2 + residual + OUT store ----
    bf16x8 a2[2];
    {
        const int row = wv * 16 + (lane & 15);
        #pragma unroll
        for (int ks = 0; ks < 2; ++ks) {
            const int chunk = ks * 4 + (lane >> 4);
            a2[ks] = *(const bf16x8*)((const char*)gs + row * 128 + ((chunk ^ (row & 7)) * 16));
        }
    }
    {
        const int tloc = wv * 16 + ((lane >> 4) << 2);
        const int t = t0 + tloc;
        #pragma unroll
        for (int n = 0; n < 4; ++n) {
            const int o = n * 16 + (lane & 15);
            const float bias = cb[o];
            f32x4 racc = (f32x4){bias, bias, bias, bias};
            const unsigned short* wrow = cwb + o * 64 + (lane >> 4) * 8;
            racc = __builtin_amdgcn_mfma_f32_16x16x32_bf16(a2[0], *(const bf16x8*)(wrow), racc, 0, 0, 0);
            racc = __builtin_amdgcn_mfma_f32_16x16x32_bf16(a2[1], *(const bf16x8*)(wrow + 32), racc, 0, 0, 0);
            const float* resp = src + (size_t)o * LL0 + t + d;
            float* outp = nxt + (size_t)b * CC * LL0 + (size_t)o * LL0 + t;
            if (t + 3 < Lout && (d & 3) == 0) {
                const float4 x1 = *(const float4*)resp;
                *(float4*)outp = (float4){racc[0] + x1.x, racc[1] + x1.y,
                                          racc[2] + x1.z, racc[3] + x1.w};
            } else {
                #pragma unroll
                for (int r = 0; r < 4; ++r)
                    if (t + r < Lout) outp[r] = racc[r] + resp[r];
            }
        }
    }

    // ---- store g window (bf16, [b][tw][64]) ----
    {
        const int skip_start = Lout - SKIPN;
        const int row = tid >> 2;
        const int t = t0 + row;
        if (t >= skip_start && t < Lout) {
            unsigned short* gr = g_out + ((size_t)b * SKIPN + (t - skip_start)) * CC;
            #pragma unroll
            for (int q = 0; q < 2; ++q) {
                const int chunk = (tid & 3) * 2 + q;
                bf16x8 vv = *(const bf16x8*)((const char*)gs + row * 128 + ((chunk ^ (row & 7)) * 16));
                *(bf16x8*)(gr + chunk * 8) = vv;
            }
        }
    }
}

// ---- deferred skip GEMMs: S^T[t][sc] = G^T[t][k] . SW[sc][k]^T + sb ----
__global__ __launch_bounds__(256) void skip_kernel(
    const unsigned short* __restrict__ g_all,   // [NBLK][BB][SKIPN][CC]
    const unsigned short* __restrict__ swb,     // [NBLK][SCC][CC]
    const float* __restrict__ skip_b,           // [NBLK][SCC]
    float* __restrict__ out)                    // [NBLK][BB][SCC][SKIPN]
{
    const int ntile = SKIPN / TT;  // 64
    const int tid = threadIdx.x, lane = tid & 63, wv = tid >> 6;
    int id = blockIdx.x;
    const int tt = id % ntile; id /= ntile;
    const int b  = id % BB;    id /= BB;
    const int blk = id;

    const unsigned short* g  = g_all + ((size_t)blk * BB + b) * SKIPN * CC;
    const unsigned short* sw = swb + (size_t)blk * SCC * CC;
    const float* sb = skip_b + blk * SCC;
    float* op = out + ((size_t)blk * BB + b) * SCC * SKIPN;

    const int trow = tt * TT + wv * 16 + (lane & 15);
    bf16x8 a[2];
    #pragma unroll
    for (int ks = 0; ks < 2; ++ks)
        a[ks] = *(const bf16x8*)(g + (size_t)trow * CC + ks * 32 + (lane >> 4) * 8);

    const int tstore = tt * TT + wv * 16 + ((lane >> 4) << 2);
    #pragma unroll 4
    for (int n = 0; n < 16; ++n) {
        const int sc = n * 16 + (lane & 15);
        const float bias = sb[sc];
        f32x4 acc = (f32x4){bias, bias, bias, bias};
        const unsigned short* wrow = sw + sc * CC + (lane >> 4) * 8;
        acc = __builtin_amdgcn_mfma_f32_16x16x32_bf16(a[0], *(const bf16x8*)(wrow), acc, 0, 0, 0);
        acc = __builtin_amdgcn_mfma_f32_16x16x32_bf16(a[1], *(const bf16x8*)(wrow + 32), acc, 0, 0, 0);
        *(float4*)(op + (size_t)sc * SKIPN + tstore) = (float4){acc[0], acc[1], acc[2], acc[3]};
    }
}

extern "C" void kernel_launch(void* const* d_in, const int* in_sizes, int n_in,
                              void* d_out, int out_size, void* d_ws, size_t ws_size,
                              hipStream_t stream)
{
    const float* x      = (const float*)d_in[0];
    const float* dc_w   = (const float*)d_in[1];
    const float* dc_b   = (const float*)d_in[2];
    const float* conv_w = (const float*)d_in[3];
    const float* conv_b = (const float*)d_in[4];
    const float* skip_w = (const float*)d_in[5];
    const float* skip_b = (const float*)d_in[6];
    float* out = (float*)d_out;

    // workspace layout
    char* ws = (char*)d_ws;
    float* buf0 = (float*)ws;                                   ws += (size_t)BB * CC * LL0 * 4;
    float* buf1 = (float*)ws;                                   ws += (size_t)BB * CC * LL0 * 4;
    unsigned short* g_all = (unsigned short*)ws;                ws += (size_t)NBLK * BB * SKIPN * CC * 2;
    unsigned short* wcat  = (unsigned short*)ws;                ws += (size_t)NBLK * CC * 128 * 2;
    unsigned short* cwb   = (unsigned short*)ws;                ws += (size_t)NBLK * CC * CC * 2;
    unsigned short* swb   = (unsigned short*)ws;                ws += (size_t)NBLK * SCC * CC * 2;
    // ~103 MB total

    hipMemcpyAsync(buf0, x, (size_t)BB * CC * LL0 * sizeof(float),
                   hipMemcpyDeviceToDevice, stream);
    prep_weights<<<1024, 256, 0, stream>>>(dc_w, conv_w, skip_w, wcat, cwb, swb);

    int dil[NBLK];
    for (int s = 0; s < 4; ++s)
        for (int l = 0; l < 10; ++l) dil[s * 10 + l] = 1 << l;

    int Lc = LL0;
    for (int i = 0; i < NBLK; ++i) {
        const int d = dil[i];
        const int Lout = Lc - d;
        const int ntiles = (Lout + TT - 1) / TT;
        const float* curp = (i & 1) ? buf1 : buf0;
        float*       nxtp = (i & 1) ? buf0 : buf1;
        block_kernel<<<dim3(BB * ntiles), 256, 0, stream>>>(
            curp, nxtp,
            wcat + (size_t)i * CC * 128, cwb + (size_t)i * CC * CC,
            dc_b + i * CC, conv_b + i * CC,
            g_all + ((size_t)i * BB) * SKIPN * CC,
            d, Lc, Lout, ntiles);
        Lc = Lout;
    }

    skip_kernel<<<dim3(NBLK * BB * (SKIPN / TT)), 256, 0, stream>>>(
        g_all, swb, skip_b, out);
}